// Round 10
// baseline (796.856 us; speedup 1.0000x reference)
//
#include <hip/hip_runtime.h>
#include <math.h>

#define NB 32
#define NN 4096
#define DK 256
#define DV 256
#define ROWS 32

// ---- branch-free double exp, f32-CR (same as R9; frozen contract) ----
__device__ __forceinline__ float fexp_cr(float xf) {
  const double INV_LN2 = 1.4426950408889634;
  const double LN2_HI = 6.93147180369123816490e-01;
  const double LN2_LO = 1.90821492927058770002e-10;
  double xd = (double)xf;
  double qd = floor(fma(xd, INV_LN2, 0.5));
  double r = fma(qd, -LN2_HI, xd);
  r = fma(qd, -LN2_LO, r);
  double p = 2.755731922398589e-7;
  p = fma(p, r, 2.7557319223985893e-6);
  p = fma(p, r, 2.48015873015873e-5);
  p = fma(p, r, 1.984126984126984e-4);
  p = fma(p, r, 1.3888888888888889e-3);
  p = fma(p, r, 8.333333333333333e-3);
  p = fma(p, r, 4.1666666666666664e-2);
  p = fma(p, r, 1.6666666666666666e-1);
  p = fma(p, r, 5.0e-1);
  p = fma(p, r, 1.0);
  p = fma(p, r, 1.0);
  long long sb = ((long long)(1023 + (int)qd)) << 52;
  double s = __longlong_as_double(sb);
  return (float)(p * s);
}

// ---- K1: H prep (frozen bit-path) ----
__global__ __launch_bounds__(256) void k_hprep(const float* __restrict__ H,
    float* __restrict__ Hn, float* __restrict__ HT) {
  const int b = blockIdx.x;
  const int t = threadIdx.x;
  const float* __restrict__ Hb = H + (size_t)b * DK * DV;

  float ss = 0.0f;
  for (int d = 0; d < DK; ++d) {
    float h = Hb[d * DV + t];
    ss = __fadd_rn(ss, __fmul_rn(h, h));
  }
  __shared__ float nr[DV];
  nr[t] = fmaxf(__fsqrt_rn(ss), 1e-8f);
  __syncthreads();

  for (int d = 0; d < DK; ++d) {
    float h = Hb[d * DV + t];
    Hn[(size_t)b * DK * DV + d * DV + t] = __fdiv_rn(h, nr[t]);
  }

  __shared__ float tile[32][33];
  const int c = t & 31, g = t >> 5;
  for (int k0 = 0; k0 < DV; k0 += 32) {
    for (int d0 = 0; d0 < DK; d0 += 32) {
      __syncthreads();
#pragma unroll
      for (int j = 0; j < 4; ++j) {
        int dl = g + 8 * j;
        tile[dl][c] = Hb[(size_t)(d0 + dl) * DV + k0 + c];
      }
      __syncthreads();
#pragma unroll
      for (int j = 0; j < 4; ++j) {
        int kl = g + 8 * j;
        HT[(size_t)b * DV * DK + (size_t)(k0 + kl) * DK + d0 + c] = tile[c][kl];
      }
    }
  }
}

// ---- K2: C row norms (strict sequential chain, frozen) -> Cn written to d_out.
// One thread per row; fully parallel across 131072 rows.
__global__ __launch_bounds__(256) void k_cnorm(const float* __restrict__ C,
                                               float* __restrict__ Cn) {
  const size_t row = (size_t)blockIdx.x * 256 + threadIdx.x;
  const float* __restrict__ cr = C + row * DK;
  float ss = 0.0f;
  for (int d = 0; d < DK; ++d) {
    float c = cr[d];
    ss = __fadd_rn(ss, __fmul_rn(c, c));
  }
  const float nrm = fmaxf(__fsqrt_rn(ss), 1e-8f);
  float* __restrict__ outr = Cn + row * DK;
  for (int d = 0; d < DK; ++d)
    outr[d] = __fdiv_rn(cr[d], nrm);
}

// ---- K3: main. GEMM with C from SGPRs (block-uniform loads), u32-key selection.
// Cn aliases d_out: each block reads ONLY its own 32 rows, then overwrites them.
__global__ __launch_bounds__(256) void k_main(
    const float* __restrict__ Cn, const float* __restrict__ Hn,
    const float* __restrict__ HT, const float* __restrict__ temp,
    float* __restrict__ out) {
  const int b = blockIdx.x >> 7;
  const int n0 = (blockIdx.x & 127) * ROWS;
  const int t = threadIdx.x;
  const int w = t >> 6, l = t & 63;

  __shared__ float xsm[ROWS * 258];
  __shared__ float m32[ROWS];
  __shared__ float zrow[ROWS];
#define XS(r, k) xsm[(r) * 258 + (k)]

  const float tt = fmaxf(temp[0], 0.1f);
  const float tp = __fadd_rn(tt, 1e-8f);

  // ---- sims GEMM: thread = column t, 32 rows; C via uniform (scalar) loads ----
  const float* __restrict__ Cnb = Cn + ((size_t)b * NN + n0) * DK;  // block-uniform
  const float* __restrict__ Hnb = Hn + (size_t)b * DK * DV;
  float acc[ROWS];
#pragma unroll
  for (int r = 0; r < ROWS; ++r) acc[r] = 0.0f;
#pragma unroll 1
  for (int d0 = 0; d0 < DK; d0 += 4) {
    const float h0 = Hnb[(size_t)(d0 + 0) * DV + t];
    const float h1 = Hnb[(size_t)(d0 + 1) * DV + t];
    const float h2 = Hnb[(size_t)(d0 + 2) * DV + t];
    const float h3 = Hnb[(size_t)(d0 + 3) * DV + t];
#pragma unroll
    for (int r = 0; r < ROWS; ++r) {
      const float* __restrict__ cr = Cnb + r * DK + d0;   // uniform address
      acc[r] = fmaf(cr[0], h0, acc[r]);
      acc[r] = fmaf(cr[1], h1, acc[r]);
      acc[r] = fmaf(cr[2], h2, acc[r]);
      acc[r] = fmaf(cr[3], h3, acc[r]);
    }
  }
  // x = fl32(sims/tp) (frozen CR div)
#pragma unroll
  for (int r = 0; r < ROWS; ++r) XS(r, t) = __fdiv_rn(acc[r], tp);
  __syncthreads();

  // ---- row max (exact): 8 threads per row ----
  {
    const int r = t >> 3, j0 = t & 7;
    float m = XS(r, j0);
#pragma unroll
    for (int i = 1; i < 32; ++i) m = fmaxf(m, XS(r, j0 + 8 * i));
    m = fmaxf(m, __shfl_xor(m, 1, 64));
    m = fmaxf(m, __shfl_xor(m, 2, 64));
    m = fmaxf(m, __shfl_xor(m, 4, 64));
    if (j0 == 0) m32[r] = m;
  }
  __syncthreads();

  // ---- e = CR exp(x - m) in place (frozen) ----
  for (int r = 0; r < ROWS; ++r)
    XS(r, t) = fexp_cr(__fsub_rn(XS(r, t), m32[r]));
  __syncthreads();

  // ---- Z: STRICT SEQUENTIAL 256-chain per row (frozen) ----
  if (t < ROWS) {
    float zacc = 0.0f;
    for (int k = 0; k < DV; ++k) zacc = __fadd_rn(zacc, XS(t, k));
    zrow[t] = zacc;
  }
  __syncthreads();

  // ---- selection + output: 8 rows per wave; u32 keys + ballot tie-resolve ----
  for (int rr = 0; rr < 8; ++rr) {
    const int r = w * 8 + rr;
    const int grow = b * NN + n0 + r;
    const float Z = zrow[r];
    // alpha = fl32(e/Z) (frozen CR div); alpha>0 so u32 bit order == value order
    unsigned int k0 = __float_as_uint(__fdiv_rn(XS(r, l), Z));
    unsigned int k1 = __float_as_uint(__fdiv_rn(XS(r, l + 64), Z));
    unsigned int k2 = __float_as_uint(__fdiv_rn(XS(r, l + 128), Z));
    unsigned int k3 = __float_as_uint(__fdiv_rn(XS(r, l + 192), Z));

    float aval[16];
    int idx[16];
#pragma unroll
    for (int e = 0; e < 16; ++e) {
      unsigned int loc = k0 > k1 ? k0 : k1;
      unsigned int l2 = k2 > k3 ? k2 : k3;
      loc = loc > l2 ? loc : l2;
#pragma unroll
      for (int s = 1; s < 64; s <<= 1) {
        unsigned int o = __shfl_xor(loc, s, 64);
        loc = o > loc ? o : loc;
      }
      // loc = max key (uniform). Lowest column index attaining it:
      unsigned long long b0 = __ballot(k0 == loc);
      unsigned long long b1 = __ballot(k1 == loc);
      unsigned long long b2 = __ballot(k2 == loc);
      unsigned long long b3 = __ballot(k3 == loc);
      int id;
      if (b0)      id = __ffsll(b0) - 1;
      else if (b1) id = 64 + __ffsll(b1) - 1;
      else if (b2) id = 128 + __ffsll(b2) - 1;
      else         id = 192 + __ffsll(b3) - 1;
      aval[e] = __uint_as_float(loc);
      idx[e] = id;
      const int owner = id & 63;
      const int slot = id >> 6;            // uniform
      if (l == owner) {
        if (slot == 0) k0 = 0u;
        else if (slot == 1) k1 = 0u;
        else if (slot == 2) k2 = 0u;
        else k3 = 0u;
      }
    }

    float S = aval[0];
#pragma unroll
    for (int e = 1; e < 16; ++e) S = __fadd_rn(S, aval[e]);
    const float S1 = __fadd_rn(S, 1e-8f);
    const float rS = __frcp_rn(S1);

    float o0 = 0.f, o1 = 0.f, o2 = 0.f, o3 = 0.f;
#pragma unroll
    for (int e = 0; e < 16; ++e) {
      const float wj = aval[e] * rS;
      const float* __restrict__ hr = HT + ((size_t)b * DV + idx[e]) * DK;
      o0 = fmaf(wj, hr[l], o0);
      o1 = fmaf(wj, hr[l + 64], o1);
      o2 = fmaf(wj, hr[l + 128], o2);
      o3 = fmaf(wj, hr[l + 192], o3);
    }
    float* __restrict__ orow = out + (size_t)grow * DK;
    orow[l] = o0;
    orow[l + 64] = o1;
    orow[l + 128] = o2;
    orow[l + 192] = o3;
  }
#undef XS
}

extern "C" void kernel_launch(void* const* d_in, const int* in_sizes, int n_in,
                              void* d_out, int out_size, void* d_ws, size_t ws_size,
                              hipStream_t stream) {
  const float* C = (const float*)d_in[0];
  const float* H = (const float*)d_in[1];
  const float* temp = (const float*)d_in[2];
  float* out = (float*)d_out;
  char* ws = (char*)d_ws;

  float* Hn = (float*)ws;                 // 8 MiB
  float* HT = (float*)(ws + 8388608);     // 8 MiB
  float* Cn = out;                        // normalized C lives in d_out; each
                                          // k_main block consumes its own rows
                                          // before overwriting them.

  hipLaunchKernelGGL(k_hprep, dim3(NB), dim3(256), 0, stream, H, Hn, HT);
  hipLaunchKernelGGL(k_cnorm, dim3((NB * NN) / 256), dim3(256), 0, stream, C, Cn);
  hipLaunchKernelGGL(k_main, dim3(NB * (NN / ROWS)), dim3(256), 0, stream,
                     Cn, Hn, HT, temp, out);
}

// Round 11
// 535.481 us; speedup vs baseline: 1.4881x; 1.4881x over previous
//
#include <hip/hip_runtime.h>
#include <math.h>

#define NB 32
#define NN 4096
#define DK 256
#define DV 256
#define ROWS 32

// ---- branch-free double exp, f32-CR (frozen contract, proven R9/R10) ----
__device__ __forceinline__ float fexp_cr(float xf) {
  const double INV_LN2 = 1.4426950408889634;
  const double LN2_HI = 6.93147180369123816490e-01;
  const double LN2_LO = 1.90821492927058770002e-10;
  double xd = (double)xf;
  double qd = floor(fma(xd, INV_LN2, 0.5));
  double r = fma(qd, -LN2_HI, xd);
  r = fma(qd, -LN2_LO, r);
  double p = 2.755731922398589e-7;
  p = fma(p, r, 2.7557319223985893e-6);
  p = fma(p, r, 2.48015873015873e-5);
  p = fma(p, r, 1.984126984126984e-4);
  p = fma(p, r, 1.3888888888888889e-3);
  p = fma(p, r, 8.333333333333333e-3);
  p = fma(p, r, 4.1666666666666664e-2);
  p = fma(p, r, 1.6666666666666666e-1);
  p = fma(p, r, 5.0e-1);
  p = fma(p, r, 1.0);
  p = fma(p, r, 1.0);
  long long sb = ((long long)(1023 + (int)qd)) << 52;
  double s = __longlong_as_double(sb);
  return (float)(p * s);
}

// ---- K1: H prep (frozen bit-path) ----
__global__ __launch_bounds__(256) void k_hprep(const float* __restrict__ H,
    float* __restrict__ Hn, float* __restrict__ HT) {
  const int b = blockIdx.x;
  const int t = threadIdx.x;
  const float* __restrict__ Hb = H + (size_t)b * DK * DV;

  float ss = 0.0f;
  for (int d = 0; d < DK; ++d) {
    float h = Hb[d * DV + t];
    ss = __fadd_rn(ss, __fmul_rn(h, h));
  }
  __shared__ float nr[DV];
  nr[t] = fmaxf(__fsqrt_rn(ss), 1e-8f);
  __syncthreads();

  for (int d = 0; d < DK; ++d) {
    float h = Hb[d * DV + t];
    Hn[(size_t)b * DK * DV + d * DV + t] = __fdiv_rn(h, nr[t]);
  }

  __shared__ float tile[32][33];
  const int c = t & 31, g = t >> 5;
  for (int k0 = 0; k0 < DV; k0 += 32) {
    for (int d0 = 0; d0 < DK; d0 += 32) {
      __syncthreads();
#pragma unroll
      for (int j = 0; j < 4; ++j) {
        int dl = g + 8 * j;
        tile[dl][c] = Hb[(size_t)(d0 + dl) * DV + k0 + c];
      }
      __syncthreads();
#pragma unroll
      for (int j = 0; j < 4; ++j) {
        int kl = g + 8 * j;
        HT[(size_t)b * DV * DK + (size_t)(k0 + kl) * DK + d0 + c] = tile[c][kl];
      }
    }
  }
}

// ---- K2: 32 rows/block; xs overlays cs (33KB LDS, 4 blocks/CU).
// All frozen bit-paths identical to R9; selection = R10's u32+ballot (verified).
__global__ __launch_bounds__(256) void k_main(
    const float* __restrict__ C, const float* __restrict__ Hn,
    const float* __restrict__ HT, const float* __restrict__ temp,
    float* __restrict__ out) {
  const int b = blockIdx.x >> 7;
  const int n0 = (blockIdx.x & 127) * ROWS;
  const int t = threadIdx.x;
  const int w = t >> 6, l = t & 63;

  __shared__ float smem[ROWS * 260];   // cs[r][260] then overlaid by xs[r][258]
  __shared__ float nrm32[ROWS];
  __shared__ float m32[ROWS];
  __shared__ float zrow[ROWS];
#define CS(r, d) smem[(r) * 260 + (d)]
#define XS(r, k) smem[(r) * 258 + (k)]

  const float* __restrict__ Cb = C + ((size_t)b * NN + n0) * DK;
  for (int i = t; i < ROWS * DK; i += 256) CS(i >> 8, i & 255) = Cb[i];
  __syncthreads();

  // C row norms: STRICT SEQUENTIAL 256-chain (frozen), 32 rows in parallel
  if (t < ROWS) {
    float ss = 0.0f;
    for (int d = 0; d < DK; ++d) {
      float c = CS(t, d);
      ss = __fadd_rn(ss, __fmul_rn(c, c));
    }
    nrm32[t] = fmaxf(__fsqrt_rn(ss), 1e-8f);
  }
  __syncthreads();
  for (int i = t; i < ROWS * DK; i += 256) {
    const int r = i >> 8, d = i & 255;
    CS(r, d) = __fdiv_rn(CS(r, d), nrm32[r]);
  }
  __syncthreads();

  const float tt = fmaxf(temp[0], 0.1f);
  const float tp = __fadd_rn(tt, 1e-8f);

  // sims GEMM: thread = 2 cols x 16 rows; ascending-d fmaf chains (frozen)
  const int rbase = (t >> 7) * 16;
  const int c0 = t & 127;
  const int c1 = c0 + 128;
  float acc0[16], acc1[16];
#pragma unroll
  for (int n = 0; n < 16; ++n) { acc0[n] = 0.0f; acc1[n] = 0.0f; }
  const float* __restrict__ Hnb = Hn + (size_t)b * DK * DV;
  for (int d0 = 0; d0 < DK; d0 += 4) {
    const float ha0 = Hnb[(size_t)(d0 + 0) * DV + c0];
    const float ha1 = Hnb[(size_t)(d0 + 1) * DV + c0];
    const float ha2 = Hnb[(size_t)(d0 + 2) * DV + c0];
    const float ha3 = Hnb[(size_t)(d0 + 3) * DV + c0];
    const float hb0 = Hnb[(size_t)(d0 + 0) * DV + c1];
    const float hb1 = Hnb[(size_t)(d0 + 1) * DV + c1];
    const float hb2 = Hnb[(size_t)(d0 + 2) * DV + c1];
    const float hb3 = Hnb[(size_t)(d0 + 3) * DV + c1];
#pragma unroll
    for (int n = 0; n < 16; ++n) {
      const float4 cv = *reinterpret_cast<const float4*>(&CS(rbase + n, d0));
      acc0[n] = fmaf(cv.x, ha0, acc0[n]);
      acc0[n] = fmaf(cv.y, ha1, acc0[n]);
      acc0[n] = fmaf(cv.z, ha2, acc0[n]);
      acc0[n] = fmaf(cv.w, ha3, acc0[n]);
      acc1[n] = fmaf(cv.x, hb0, acc1[n]);
      acc1[n] = fmaf(cv.y, hb1, acc1[n]);
      acc1[n] = fmaf(cv.z, hb2, acc1[n]);
      acc1[n] = fmaf(cv.w, hb3, acc1[n]);
    }
  }
  __syncthreads();   // all cs reads done before xs overlay writes

  // x = fl32(sims/tp) (frozen CR div), into overlaid xs
#pragma unroll
  for (int n = 0; n < 16; ++n) {
    XS(rbase + n, c0) = __fdiv_rn(acc0[n], tp);
    XS(rbase + n, c1) = __fdiv_rn(acc1[n], tp);
  }
  __syncthreads();

  // row max (exact): 8 threads per row
  {
    const int r = t >> 3, j0 = t & 7;
    float m = XS(r, j0);
#pragma unroll
    for (int i = 1; i < 32; ++i) m = fmaxf(m, XS(r, j0 + 8 * i));
    m = fmaxf(m, __shfl_xor(m, 1, 64));
    m = fmaxf(m, __shfl_xor(m, 2, 64));
    m = fmaxf(m, __shfl_xor(m, 4, 64));
    if (j0 == 0) m32[r] = m;
  }
  __syncthreads();

  // e = CR exp(x - m) in place (frozen)
  for (int r = 0; r < ROWS; ++r)
    XS(r, t) = fexp_cr(__fsub_rn(XS(r, t), m32[r]));
  __syncthreads();

  // Z: STRICT SEQUENTIAL 256-chain per row (frozen)
  if (t < ROWS) {
    float zacc = 0.0f;
    for (int k = 0; k < DV; ++k) zacc = __fadd_rn(zacc, XS(t, k));
    zrow[t] = zacc;
  }
  __syncthreads();

  // selection + output: 8 rows per wave; u32 keys + ballot tie-resolve (R10, verified)
  for (int rr = 0; rr < 8; ++rr) {
    const int r = w * 8 + rr;
    const int grow = b * NN + n0 + r;
    const float Z = zrow[r];
    // alpha = fl32(e/Z) (frozen CR div); alpha>=0 so u32 bit order == value order
    unsigned int k0 = __float_as_uint(__fdiv_rn(XS(r, l), Z));
    unsigned int k1 = __float_as_uint(__fdiv_rn(XS(r, l + 64), Z));
    unsigned int k2 = __float_as_uint(__fdiv_rn(XS(r, l + 128), Z));
    unsigned int k3 = __float_as_uint(__fdiv_rn(XS(r, l + 192), Z));

    float aval[16];
    int idx[16];
#pragma unroll
    for (int e = 0; e < 16; ++e) {
      unsigned int loc = k0 > k1 ? k0 : k1;
      unsigned int l2 = k2 > k3 ? k2 : k3;
      loc = loc > l2 ? loc : l2;
#pragma unroll
      for (int s = 1; s < 64; s <<= 1) {
        unsigned int o = __shfl_xor(loc, s, 64);
        loc = o > loc ? o : loc;
      }
      // loc = max key (uniform). Lowest column index attaining it:
      unsigned long long b0 = __ballot(k0 == loc);
      unsigned long long b1 = __ballot(k1 == loc);
      unsigned long long b2 = __ballot(k2 == loc);
      unsigned long long b3 = __ballot(k3 == loc);
      int id;
      if (b0)      id = __ffsll(b0) - 1;
      else if (b1) id = 64 + __ffsll(b1) - 1;
      else if (b2) id = 128 + __ffsll(b2) - 1;
      else         id = 192 + __ffsll(b3) - 1;
      aval[e] = __uint_as_float(loc);
      idx[e] = id;
      const int owner = id & 63;
      const int slot = id >> 6;            // uniform
      if (l == owner) {
        if (slot == 0) k0 = 0u;
        else if (slot == 1) k1 = 0u;
        else if (slot == 2) k2 = 0u;
        else k3 = 0u;
      }
    }

    float S = aval[0];
#pragma unroll
    for (int e = 1; e < 16; ++e) S = __fadd_rn(S, aval[e]);
    const float S1 = __fadd_rn(S, 1e-8f);
    const float rS = __frcp_rn(S1);

    float o0 = 0.f, o1 = 0.f, o2 = 0.f, o3 = 0.f;
#pragma unroll
    for (int e = 0; e < 16; ++e) {
      const float wj = aval[e] * rS;
      const float* __restrict__ hr = HT + ((size_t)b * DV + idx[e]) * DK;
      o0 = fmaf(wj, hr[l], o0);
      o1 = fmaf(wj, hr[l + 64], o1);
      o2 = fmaf(wj, hr[l + 128], o2);
      o3 = fmaf(wj, hr[l + 192], o3);
    }
    float* __restrict__ orow = out + (size_t)grow * DK;
    orow[l] = o0;
    orow[l + 64] = o1;
    orow[l + 128] = o2;
    orow[l + 192] = o3;
  }
#undef CS
#undef XS
}

extern "C" void kernel_launch(void* const* d_in, const int* in_sizes, int n_in,
                              void* d_out, int out_size, void* d_ws, size_t ws_size,
                              hipStream_t stream) {
  const float* C = (const float*)d_in[0];
  const float* H = (const float*)d_in[1];
  const float* temp = (const float*)d_in[2];
  float* out = (float*)d_out;
  char* ws = (char*)d_ws;

  float* Hn = (float*)ws;                 // 8 MiB
  float* HT = (float*)(ws + 8388608);     // 8 MiB

  hipLaunchKernelGGL(k_hprep, dim3(NB), dim3(256), 0, stream, H, Hn, HT);
  hipLaunchKernelGGL(k_main, dim3(NB * (NN / ROWS)), dim3(256), 0, stream,
                     C, Hn, HT, temp, out);
}